// Round 2
// baseline (494.937 us; speedup 1.0000x reference)
//
#include <hip/hip_runtime.h>
#include <hip/hip_cooperative_groups.h>
#include <math.h>

namespace cg = cooperative_groups;

#define N 16384
#define GC 8             // grid cells per dim (margin >= 1/8 -> fallback ~never fires)
#define NCELL (GC*GC*GC) // 512
#define NBLK 512         // cooperative grid: 2 blocks/CU on 256 CUs
#define NTHR 256
#define NWAVE ((NBLK*NTHR)/64)   // 2048 waves

__device__ __forceinline__ float wsum(float v){
  #pragma unroll
  for(int m=32;m>0;m>>=1) v += __shfl_xor(v,m,64);
  return v;
}

// branchless lexicographic (d,idx) top-3 insert; matches jax top_k stable tie-break
__device__ __forceinline__ void lexins(float dd,int j2,
    float&D0,float&D1,float&D2,int&I0,int&I1,int&I2){
  bool lt0=(dd<D0)||((dd==D0)&&(j2<I0));
  bool lt1=(dd<D1)||((dd==D1)&&(j2<I1));
  bool lt2=(dd<D2)||((dd==D2)&&(j2<I2));
  float nD2=lt1?D1:(lt2?dd:D2); int nI2=lt1?I1:(lt2?j2:I2);
  float nD1=lt0?D0:(lt1?dd:D1); int nI1=lt0?I0:(lt1?j2:I1);
  float nD0=lt0?dd:D0;          int nI0=lt0?j2:I0;
  D0=nD0;D1=nD1;D2=nD2;I0=nI0;I1=nI1;I2=nI2;
}

// reference-exact squared distance: dd = rn(rn(qs+cs) - 2*dot), dot FMA chain
__device__ __forceinline__ float refdist(float qx,float qy,float qz,float qs,float4 cv){
  float dot=__fmaf_rn(qz,cv.z,__fmaf_rn(qy,cv.y,__fmul_rn(qx,cv.x)));
  float sc =__fadd_rn(qs,cv.w);
  return __fmaf_rn(-2.0f,dot,sc);
}

__device__ __forceinline__ int cellOf(float4 v){
  int cx=min(GC-1,(int)(v.x*(float)GC)), cy=min(GC-1,(int)(v.y*(float)GC)),
      cz=min(GC-1,(int)(v.z*(float)GC));
  return (cz*GC+cy)*GC+cx;
}

struct Params {
  const float *feat,*coords,*g1,*b1,*g2,*b2,*gg,*gb,*W1,*bb1,*W2,*bb2;
  float *out;
  float *x,*a1,*xn,*ew,*dis;
  int *knn; float4 *c4,*sc4; int *sidx,*cellSt,*cursor;
};

// ================= fused cooperative kernel: 6 dispatches -> 1 ==============
// Phases separated by grid.sync(); all cross-phase producer->consumer pairs
// cross a sync (release+acquire device fence). No CU re-reads a line it cached
// before a remote write (histogram recomputed in LDS; cursors atomic-only).
__global__ __launch_bounds__(256,2) void fused(Params P){
  cg::grid_group grid = cg::this_grid();
  int tid=threadIdx.x, bid=blockIdx.x;
  int gtid=bid*NTHR+tid;
  int lane=tid&63, wave=tid>>6;
  int gwave=gtid>>6;                 // [0, 2048)
  __shared__ float rowbuf[4][64];    // agg phases
  __shared__ int smem[2*NCELL];      // block0 hist+scan (4KB)

  // ---- Phase 0: zero cursors; LN -> x2 -> LN; row norms; c4. 8 rows/wave ----
  if(gtid<NCELL) P.cursor[gtid]=0;
  #pragma unroll 1
  for(int rr=0;rr<8;rr++){
    int row=gwave*8+rr;
    float v=P.feat[row*64+lane];
    float m=wsum(v)*(1.0f/64.0f);
    float d=v-m;
    float var=wsum(d*d)*(1.0f/64.0f);
    float y=d*(1.0f/sqrtf(var+1e-5f))*P.g1[lane]+P.b1[lane];
    y=y+y;  // transformer stubbed as identity + shortcut
    float m2=wsum(y)*(1.0f/64.0f);
    float d2=y-m2;
    float var2=wsum(d2*d2)*(1.0f/64.0f);
    float z=d2*(1.0f/sqrtf(var2+1e-5f))*P.g2[lane]+P.b2[lane];
    P.x[row*64+lane]=z;
    float s=wsum(z*z);
    if(lane==0){
      P.xn[row]=fmaxf(sqrtf(s),1e-8f);
      float a=P.coords[row*3+0],b=P.coords[row*3+1],c=P.coords[row*3+2];
      float sq=__fadd_rn(__fadd_rn(__fmul_rn(a,a),__fmul_rn(b,b)),__fmul_rn(c,c));
      P.c4[row]=make_float4(a,b,c,sq);
    }
  }
  grid.sync();

  // ---- Phase 1: block 0 builds histogram (from c4, fresh lines) + scan ----
  if(bid==0){
    for(int i=tid;i<NCELL;i+=NTHR) smem[i]=0;
    __syncthreads();
    for(int i=tid;i<N;i+=NTHR){
      atomicAdd(&smem[cellOf(P.c4[i])],1);
    }
    __syncthreads();
    for(int i=tid;i<NCELL;i+=NTHR) smem[NCELL+i]=smem[i];
    __syncthreads();
    for(int off=1;off<NCELL;off<<=1){
      int v0=(tid>=off)?smem[NCELL+tid-off]:0;
      int v1=((tid+256)>=off)?smem[NCELL+tid+256-off]:0;
      __syncthreads();
      smem[NCELL+tid]+=v0; smem[NCELL+tid+256]+=v1;
      __syncthreads();
    }
    P.cellSt[tid]    =smem[NCELL+tid]    -smem[tid];      // exclusive starts
    P.cellSt[tid+256]=smem[NCELL+tid+256]-smem[tid+256];
    if(tid==0) P.cellSt[NCELL]=N;
  }
  grid.sync();

  // ---- Phase 1c: distributed scatter (within-cell order nondeterministic; ok:
  // top-3 uses full lexicographic (d,idx) tie-break) ----
  if(gtid<N){
    float4 v=P.c4[gtid];
    int cell=cellOf(v);
    int pos=P.cellSt[cell]+atomicAdd(&P.cursor[cell],1);
    P.sc4[pos]=v; P.sidx[pos]=gtid;
  }
  grid.sync();

  // ---- Phase 2: grid KNN (32 lanes/query) + edge weights. 4 passes. ----
  #pragma unroll 1
  for(int pass=0;pass<4;pass++){
    int slot=pass*4096+(gwave<<1)+(lane>>5);
    int part=lane&31;
    float4 qv=P.sc4[slot]; int q=P.sidx[slot];
    float qx=qv.x,qy=qv.y,qz=qv.z,qs=qv.w;
    int cx=min(GC-1,(int)(qx*(float)GC)), cy=min(GC-1,(int)(qy*(float)GC)),
        cz=min(GC-1,(int)(qz*(float)GC));
    float D0=1e30f,D1=1e30f,D2=1e30f; int I0=0x7fffffff,I1=0x7fffffff,I2=0x7fffffff;
    int xlo=max(cx-1,0), xhi=min(cx+1,GC-1);
    const float cw=1.0f/(float)GC;
    float fy0=qy-(float)cy*cw, fy1=(float)(cy+1)*cw-qy;   // dist to y faces
    float fz0=qz-(float)cz*cw, fz1=(float)(cz+1)*cw-qz;   // dist to z faces
    // run order: center, 4 faces, 4 diagonals  (oy, oz)
    const int OY[9]={0,-1,1, 0,0,-1, 1,-1,1};
    const int OZ[9]={0, 0,0,-1,1,-1,-1, 1,1};
    #pragma unroll 1
    for(int k=0;k<9;k++){
      int oy=OY[k], oz=OZ[k];
      int y2=cy+oy, z2=cz+oz;
      if(y2<0||y2>=GC||z2<0||z2>=GC) continue;
      if(k>0){
        float dy=(oy<0)?fy0:((oy>0)?fy1:0.0f);
        float dz=(oz<0)?fz0:((oz>0)?fz1:0.0f);
        float bnd=dy*dy+dz*dz;
        if(bnd>D2+1e-5f) continue;          // conservative skip
      }
      int rowb=(z2*GC+y2)*GC;
      int p0=P.cellSt[rowb+xlo], p1=P.cellSt[rowb+xhi+1];  // x-cells contiguous
      for(int p=p0+part;p<p1;p+=32){
        float4 cv=P.sc4[p]; int j2=P.sidx[p];
        float dd=refdist(qx,qy,qz,qs,cv);
        dd=(j2==q)?1e30f:dd;
        lexins(dd,j2,D0,D1,D2,I0,I1,I2);
      }
    }
    #pragma unroll
    for(int m=1;m<32;m<<=1){
      float e0=__shfl_xor(D0,m),e1=__shfl_xor(D1,m),e2=__shfl_xor(D2,m);
      int   f0=__shfl_xor(I0,m),f1=__shfl_xor(I1,m),f2=__shfl_xor(I2,m);
      lexins(e0,f0,D0,D1,D2,I0,I1,I2);
      lexins(e1,f1,D0,D1,D2,I0,I1,I2);
      lexins(e2,f2,D0,D1,D2,I0,I1,I2);
    }
    bool flg=false;
    if(part==0){
      float mg=1e30f;
      mg=fminf(mg,(cx>0)?(qx-(float)(cx-1)*cw):1e30f);
      mg=fminf(mg,(cx<GC-1)?((float)(cx+2)*cw-qx):1e30f);
      mg=fminf(mg,(cy>0)?(qy-(float)(cy-1)*cw):1e30f);
      mg=fminf(mg,(cy<GC-1)?((float)(cy+2)*cw-qy):1e30f);
      mg=fminf(mg,(cz>0)?(qz-(float)(cz-1)*cw):1e30f);
      mg=fminf(mg,(cz<GC-1)?((float)(cz+2)*cw-qz):1e30f);
      float mg2=mg*mg*(1.0f-1e-5f);   // slack for dd rounding
      flg=!(D2<mg2);                  // at GC=8: ~never true
    }
    // safety-net fallback, expected ~0 queries
    unsigned long long mask=__ballot(flg);
    while(mask){
      int b=__ffsll((unsigned long long)mask)-1; mask&=mask-1;
      int qb=__shfl(q,b);
      float bx=__shfl(qx,b),by=__shfl(qy,b),bz=__shfl(qz,b),bs=__shfl(qs,b);
      float E0=1e30f,E1=1e30f,E2=1e30f; int F0=0x7fffffff,F1=0x7fffffff,F2=0x7fffffff;
      for(int j=lane;j<N;j+=64){
        float4 cv=P.c4[j];
        float dd=refdist(bx,by,bz,bs,cv);
        dd=(j==qb)?1e30f:dd;
        lexins(dd,j,E0,E1,E2,F0,F1,F2);
      }
      #pragma unroll
      for(int m=1;m<64;m<<=1){
        float e0=__shfl_xor(E0,m),e1=__shfl_xor(E1,m),e2=__shfl_xor(E2,m);
        int   f0=__shfl_xor(F0,m),f1=__shfl_xor(F1,m),f2=__shfl_xor(F2,m);
        lexins(e0,f0,E0,E1,E2,F0,F1,F2);
        lexins(e1,f1,E0,E1,E2,F0,F1,F2);
        lexins(e2,f2,E0,E1,E2,F0,F1,F2);
      }
      if(lane==b){ I0=F0; I1=F1; I2=F2; }
    }
    if(part==0){ P.knn[q*3+0]=I0; P.knn[q*3+1]=I1; P.knn[q*3+2]=I2; }

    // --- ew + dis for the wave's 2 queries (neighbor loads hoisted) ---
    for(int r=0;r<2;r++){
      int qi=__shfl(q,32*r);
      int s0=__shfl(I0,32*r), s1=__shfl(I1,32*r), s2=__shfl(I2,32*r);
      float xi=P.x[qi*64+lane];
      float xs0=P.x[s0*64+lane], xs1=P.x[s1*64+lane], xs2=P.x[s2*64+lane];
      float n0=P.xn[s0], n1=P.xn[s1], n2=P.xn[s2];
      float ni=P.xn[qi];
      float dt0=wsum(xs0*xi), dt1=wsum(xs1*xi), dt2=wsum(xs2*xi);
      float e0=1.f/(1.f+expf(-(dt0/(n0*ni))));
      float e1=1.f/(1.f+expf(-(dt1/(n1*ni))));
      float e2=1.f/(1.f+expf(-(dt2/(n2*ni))));
      if(lane==0){
        P.ew[qi*3+0]=e0; P.ew[qi*3+1]=e1; P.ew[qi*3+2]=e2;
        float ssum=((e0+e1)+e2);
        P.dis[qi]=1.f/sqrtf(ssum+1.0f);         // deg = 1 (self loop) + sum(ew)
      }
    }
  }
  grid.sync();

  // ---- Phase 3: xa = weighted-agg(x); a1 = relu(LN(xa@W1+b1)). 8 nodes/wave,
  // 2-deep pipeline (stage r+1's index->gather chain under r's matvec+LN) ----
  {
    float wcol[64];
    #pragma unroll
    for(int k=0;k<64;k++) wcol[k]=P.W1[k*64+lane];   // lane L owns W1[:,L]
    float bv=P.bb1[lane], gv=P.gg[lane], bv2=P.gb[lane];
    int nb=gwave*8;
    float xrA,dAA,xsA0,xsA1,xsA2,wA0,wA1,wA2;
    float xrB,dBB,xsB0,xsB1,xsB2,wB0,wB1,wB2;
    {
      int i=nb;
      float di=P.dis[i]; dAA=di*di;
      xrA=P.x[i*64+lane];
      int s0=P.knn[i*3+0], s1=P.knn[i*3+1], s2=P.knn[i*3+2];
      xsA0=P.x[s0*64+lane]; xsA1=P.x[s1*64+lane]; xsA2=P.x[s2*64+lane];
      wA0=P.dis[s0]*P.ew[i*3+0]*di; wA1=P.dis[s1]*P.ew[i*3+1]*di; wA2=P.dis[s2]*P.ew[i*3+2]*di;
    }
    #pragma unroll 1
    for(int r=0;r<8;r++){
      if(r<7){
        int i=nb+r+1;
        float di=P.dis[i]; dBB=di*di;
        xrB=P.x[i*64+lane];
        int s0=P.knn[i*3+0], s1=P.knn[i*3+1], s2=P.knn[i*3+2];
        xsB0=P.x[s0*64+lane]; xsB1=P.x[s1*64+lane]; xsB2=P.x[s2*64+lane];
        wB0=P.dis[s0]*P.ew[i*3+0]*di; wB1=P.dis[s1]*P.ew[i*3+1]*di; wB2=P.dis[s2]*P.ew[i*3+2]*di;
      }
      float xa=xrA*dAA;
      xa=fmaf(xsA0,wA0,xa); xa=fmaf(xsA1,wA1,xa); xa=fmaf(xsA2,wA2,xa);
      rowbuf[wave][lane]=xa;                    // wave-synchronous LDS bounce
      const float4* rb=(const float4*)&rowbuf[wave][0];
      float acc=0.f;
      #pragma unroll
      for(int k4=0;k4<16;k4++){
        float4 av=rb[k4];                       // broadcast read
        acc=fmaf(av.x,wcol[k4*4+0],acc);
        acc=fmaf(av.y,wcol[k4*4+1],acc);
        acc=fmaf(av.z,wcol[k4*4+2],acc);
        acc=fmaf(av.w,wcol[k4*4+3],acc);
      }
      acc+=bv;
      float mu=wsum(acc)*(1.0f/64.0f);
      float dd=acc-mu;
      float var=wsum(dd*dd)*(1.0f/64.0f);
      float y=dd*(1.0f/sqrtf(var+1e-5f))*gv+bv2;
      P.a1[(nb+r)*64+lane]=fmaxf(y,0.0f);
      xrA=xrB; dAA=dBB;
      xsA0=xsB0; xsA1=xsB1; xsA2=xsB2;
      wA0=wB0; wA1=wB1; wA2=wB2;
    }
  }
  grid.sync();

  // ---- Phase 4: aa = weighted-agg(a1); out = aa@W2 + b2 + 2x ----
  {
    float wcol[64];
    #pragma unroll
    for(int k=0;k<64;k++) wcol[k]=P.W2[k*64+lane];
    float bv=P.bb2[lane];
    int nb=gwave*8;
    float xrA,dAA,xsA0,xsA1,xsA2,wA0,wA1,wA2;
    float xrB,dBB,xsB0,xsB1,xsB2,wB0,wB1,wB2;
    {
      int i=nb;
      float di=P.dis[i]; dAA=di*di;
      xrA=P.a1[i*64+lane];
      int s0=P.knn[i*3+0], s1=P.knn[i*3+1], s2=P.knn[i*3+2];
      xsA0=P.a1[s0*64+lane]; xsA1=P.a1[s1*64+lane]; xsA2=P.a1[s2*64+lane];
      wA0=P.dis[s0]*P.ew[i*3+0]*di; wA1=P.dis[s1]*P.ew[i*3+1]*di; wA2=P.dis[s2]*P.ew[i*3+2]*di;
    }
    #pragma unroll 1
    for(int r=0;r<8;r++){
      if(r<7){
        int i=nb+r+1;
        float di=P.dis[i]; dBB=di*di;
        xrB=P.a1[i*64+lane];
        int s0=P.knn[i*3+0], s1=P.knn[i*3+1], s2=P.knn[i*3+2];
        xsB0=P.a1[s0*64+lane]; xsB1=P.a1[s1*64+lane]; xsB2=P.a1[s2*64+lane];
        wB0=P.dis[s0]*P.ew[i*3+0]*di; wB1=P.dis[s1]*P.ew[i*3+1]*di; wB2=P.dis[s2]*P.ew[i*3+2]*di;
      }
      float aa=xrA*dAA;
      aa=fmaf(xsA0,wA0,aa); aa=fmaf(xsA1,wA1,aa); aa=fmaf(xsA2,wA2,aa);
      rowbuf[wave][lane]=aa;
      const float4* rb=(const float4*)&rowbuf[wave][0];
      float acc=0.f;
      #pragma unroll
      for(int k4=0;k4<16;k4++){
        float4 av=rb[k4];
        acc=fmaf(av.x,wcol[k4*4+0],acc);
        acc=fmaf(av.y,wcol[k4*4+1],acc);
        acc=fmaf(av.z,wcol[k4*4+2],acc);
        acc=fmaf(av.w,wcol[k4*4+3],acc);
      }
      acc+=bv;
      float xv=P.x[(nb+r)*64+lane];
      P.out[(nb+r)*64+lane]=(acc+xv)+xv;  // (gcn2 + x) + shortcut, shortcut == x
      xrA=xrB; dAA=dBB;
      xsA0=xsB0; xsA1=xsB1; xsA2=xsB2;
      wA0=wB0; wA1=wB1; wA2=wB2;
    }
  }
}

// ===================== fallback pipeline (round-1, proven) ==================
__global__ __launch_bounds__(256) void ln_kernel(const float* __restrict__ in,
    const float* __restrict__ g1,const float* __restrict__ b1,
    const float* __restrict__ g2,const float* __restrict__ b2,
    const float* __restrict__ coords,
    float* __restrict__ x, float* __restrict__ xn, float4* __restrict__ c4,
    int* __restrict__ cnt){
  int wave=threadIdx.x>>6, lane=threadIdx.x&63;
  int row=blockIdx.x*4+wave;
  float v=in[row*64+lane];
  float m=wsum(v)*(1.0f/64.0f);
  float d=v-m;
  float var=wsum(d*d)*(1.0f/64.0f);
  float y=d*(1.0f/sqrtf(var+1e-5f))*g1[lane]+b1[lane];
  y=y+y;
  float m2=wsum(y)*(1.0f/64.0f);
  float d2=y-m2;
  float var2=wsum(d2*d2)*(1.0f/64.0f);
  float z=d2*(1.0f/sqrtf(var2+1e-5f))*g2[lane]+b2[lane];
  x[row*64+lane]=z;
  float s=wsum(z*z);
  if(lane==0){
    xn[row]=fmaxf(sqrtf(s),1e-8f);
    float a=coords[row*3+0],b=coords[row*3+1],c=coords[row*3+2];
    float sq=__fadd_rn(__fadd_rn(__fmul_rn(a,a),__fmul_rn(b,b)),__fmul_rn(c,c));
    c4[row]=make_float4(a,b,c,sq);
    atomicAdd(&cnt[cellOf(make_float4(a,b,c,sq))],1);
  }
}

__global__ __launch_bounds__(256) void scatter_k(const float4* __restrict__ c4,
    const int* __restrict__ cnt, int* __restrict__ cursor,
    float4* __restrict__ sc4, int* __restrict__ sidx, int* __restrict__ cellSt){
  __shared__ int buf[NCELL];
  int tid=threadIdx.x;
  int c0v=cnt[tid], c1v=cnt[tid+256];
  buf[tid]=c0v; buf[tid+256]=c1v;
  __syncthreads();
  #pragma unroll
  for(int off=1;off<NCELL;off<<=1){
    int v0=(tid>=off)?buf[tid-off]:0;
    int v1=(tid+256>=off)?buf[tid+256-off]:0;
    __syncthreads();
    buf[tid]+=v0; buf[tid+256]+=v1;
    __syncthreads();
  }
  int e0=buf[tid]-c0v, e1=buf[tid+256]-c1v;
  if(blockIdx.x==0){
    cellSt[tid]=e0; cellSt[tid+256]=e1;
    if(tid==0) cellSt[NCELL]=N;
  }
  __syncthreads();
  buf[tid]=e0; buf[tid+256]=e1;
  __syncthreads();
  int i=blockIdx.x*256+tid;
  float4 v=c4[i];
  int cell=cellOf(v);
  int pos=buf[cell]+atomicAdd(&cursor[cell],1);
  sc4[pos]=v; sidx[pos]=i;
}

__global__ __launch_bounds__(256) void knn_ew(const float4* __restrict__ sc4,
    const int* __restrict__ sidx, const int* __restrict__ cellSt,
    const float4* __restrict__ c4, const float* __restrict__ x,
    const float* __restrict__ xn,
    int* __restrict__ knn, float* __restrict__ ew, float* __restrict__ dis){
  int tid=threadIdx.x, bid=blockIdx.x;
  int gt=bid*256+tid;
  int lane=tid&63;
  int slot=gt>>5, part=tid&31;
  float4 qv=sc4[slot]; int q=sidx[slot];
  float qx=qv.x,qy=qv.y,qz=qv.z,qs=qv.w;
  int cx=min(GC-1,(int)(qx*(float)GC)), cy=min(GC-1,(int)(qy*(float)GC)),
      cz=min(GC-1,(int)(qz*(float)GC));
  float D0=1e30f,D1=1e30f,D2=1e30f; int I0=0x7fffffff,I1=0x7fffffff,I2=0x7fffffff;
  int xlo=max(cx-1,0), xhi=min(cx+1,GC-1);
  const float cw=1.0f/(float)GC;
  float fy0=qy-(float)cy*cw, fy1=(float)(cy+1)*cw-qy;
  float fz0=qz-(float)cz*cw, fz1=(float)(cz+1)*cw-qz;
  const int OY[9]={0,-1,1, 0,0,-1, 1,-1,1};
  const int OZ[9]={0, 0,0,-1,1,-1,-1, 1,1};
  #pragma unroll 1
  for(int k=0;k<9;k++){
    int oy=OY[k], oz=OZ[k];
    int y2=cy+oy, z2=cz+oz;
    if(y2<0||y2>=GC||z2<0||z2>=GC) continue;
    if(k>0){
      float dy=(oy<0)?fy0:((oy>0)?fy1:0.0f);
      float dz=(oz<0)?fz0:((oz>0)?fz1:0.0f);
      float bnd=dy*dy+dz*dz;
      if(bnd>D2+1e-5f) continue;
    }
    int rowb=(z2*GC+y2)*GC;
    int p0=cellSt[rowb+xlo], p1=cellSt[rowb+xhi+1];
    for(int p=p0+part;p<p1;p+=32){
      float4 cv=sc4[p]; int j2=sidx[p];
      float dd=refdist(qx,qy,qz,qs,cv);
      dd=(j2==q)?1e30f:dd;
      lexins(dd,j2,D0,D1,D2,I0,I1,I2);
    }
  }
  #pragma unroll
  for(int m=1;m<32;m<<=1){
    float e0=__shfl_xor(D0,m),e1=__shfl_xor(D1,m),e2=__shfl_xor(D2,m);
    int   f0=__shfl_xor(I0,m),f1=__shfl_xor(I1,m),f2=__shfl_xor(I2,m);
    lexins(e0,f0,D0,D1,D2,I0,I1,I2);
    lexins(e1,f1,D0,D1,D2,I0,I1,I2);
    lexins(e2,f2,D0,D1,D2,I0,I1,I2);
  }
  bool flg=false;
  if(part==0){
    float mg=1e30f;
    mg=fminf(mg,(cx>0)?(qx-(float)(cx-1)*cw):1e30f);
    mg=fminf(mg,(cx<GC-1)?((float)(cx+2)*cw-qx):1e30f);
    mg=fminf(mg,(cy>0)?(qy-(float)(cy-1)*cw):1e30f);
    mg=fminf(mg,(cy<GC-1)?((float)(cy+2)*cw-qy):1e30f);
    mg=fminf(mg,(cz>0)?(qz-(float)(cz-1)*cw):1e30f);
    mg=fminf(mg,(cz<GC-1)?((float)(cz+2)*cw-qz):1e30f);
    float mg2=mg*mg*(1.0f-1e-5f);
    flg=!(D2<mg2);
  }
  unsigned long long mask=__ballot(flg);
  while(mask){
    int b=__ffsll((unsigned long long)mask)-1; mask&=mask-1;
    int qb=__shfl(q,b);
    float bx=__shfl(qx,b),by=__shfl(qy,b),bz=__shfl(qz,b),bs=__shfl(qs,b);
    float E0=1e30f,E1=1e30f,E2=1e30f; int F0=0x7fffffff,F1=0x7fffffff,F2=0x7fffffff;
    for(int j=lane;j<N;j+=64){
      float4 cv=c4[j];
      float dd=refdist(bx,by,bz,bs,cv);
      dd=(j==qb)?1e30f:dd;
      lexins(dd,j,E0,E1,E2,F0,F1,F2);
    }
    #pragma unroll
    for(int m=1;m<64;m<<=1){
      float e0=__shfl_xor(E0,m),e1=__shfl_xor(E1,m),e2=__shfl_xor(E2,m);
      int   f0=__shfl_xor(F0,m),f1=__shfl_xor(F1,m),f2=__shfl_xor(F2,m);
      lexins(e0,f0,E0,E1,E2,F0,F1,F2);
      lexins(e1,f1,E0,E1,E2,F0,F1,F2);
      lexins(e2,f2,E0,E1,E2,F0,F1,F2);
    }
    if(lane==b){ I0=F0; I1=F1; I2=F2; }
  }
  if(part==0){ knn[q*3+0]=I0; knn[q*3+1]=I1; knn[q*3+2]=I2; }
  for(int r=0;r<2;r++){
    int qi=__shfl(q,32*r);
    int s0=__shfl(I0,32*r), s1=__shfl(I1,32*r), s2=__shfl(I2,32*r);
    float xi=x[qi*64+lane];
    float xs0=x[s0*64+lane], xs1=x[s1*64+lane], xs2=x[s2*64+lane];
    float n0=xn[s0], n1=xn[s1], n2=xn[s2];
    float ni=xn[qi];
    float dt0=wsum(xs0*xi), dt1=wsum(xs1*xi), dt2=wsum(xs2*xi);
    float e0=1.f/(1.f+expf(-(dt0/(n0*ni))));
    float e1=1.f/(1.f+expf(-(dt1/(n1*ni))));
    float e2=1.f/(1.f+expf(-(dt2/(n2*ni))));
    if(lane==0){
      ew[qi*3+0]=e0; ew[qi*3+1]=e1; ew[qi*3+2]=e2;
      float ssum=((e0+e1)+e2);
      dis[qi]=1.f/sqrtf(ssum+1.0f);
    }
  }
}

__global__ __launch_bounds__(256) void agg1_w1(const float* __restrict__ x,
    const float* __restrict__ ew, const float* __restrict__ dis,
    const int* __restrict__ knn, const float* __restrict__ W1,
    const float* __restrict__ bb1, const float* __restrict__ gg,
    const float* __restrict__ gb, float* __restrict__ a1){
  __shared__ float rowbuf[4][64];
  int tid=threadIdx.x;
  int wave=tid>>6, lane=tid&63;
  float wcol[64];
  #pragma unroll
  for(int k=0;k<64;k++) wcol[k]=W1[k*64+lane];
  float bv=bb1[lane], gv=gg[lane], bv2=gb[lane];
  int nb=blockIdx.x*16+wave*4;
  float xrA,dAA,xsA0,xsA1,xsA2,wA0,wA1,wA2;
  float xrB,dBB,xsB0,xsB1,xsB2,wB0,wB1,wB2;
  {
    int i=nb;
    float di=dis[i]; dAA=di*di;
    xrA=x[i*64+lane];
    int s0=knn[i*3+0], s1=knn[i*3+1], s2=knn[i*3+2];
    xsA0=x[s0*64+lane]; xsA1=x[s1*64+lane]; xsA2=x[s2*64+lane];
    wA0=dis[s0]*ew[i*3+0]*di; wA1=dis[s1]*ew[i*3+1]*di; wA2=dis[s2]*ew[i*3+2]*di;
  }
  #pragma unroll
  for(int r=0;r<4;r++){
    if(r<3){
      int i=nb+r+1;
      float di=dis[i]; dBB=di*di;
      xrB=x[i*64+lane];
      int s0=knn[i*3+0], s1=knn[i*3+1], s2=knn[i*3+2];
      xsB0=x[s0*64+lane]; xsB1=x[s1*64+lane]; xsB2=x[s2*64+lane];
      wB0=dis[s0]*ew[i*3+0]*di; wB1=dis[s1]*ew[i*3+1]*di; wB2=dis[s2]*ew[i*3+2]*di;
    }
    float xa=xrA*dAA;
    xa=fmaf(xsA0,wA0,xa); xa=fmaf(xsA1,wA1,xa); xa=fmaf(xsA2,wA2,xa);
    rowbuf[wave][lane]=xa;
    const float4* rb=(const float4*)&rowbuf[wave][0];
    float acc=0.f;
    #pragma unroll
    for(int k4=0;k4<16;k4++){
      float4 av=rb[k4];
      acc=fmaf(av.x,wcol[k4*4+0],acc);
      acc=fmaf(av.y,wcol[k4*4+1],acc);
      acc=fmaf(av.z,wcol[k4*4+2],acc);
      acc=fmaf(av.w,wcol[k4*4+3],acc);
    }
    acc+=bv;
    float mu=wsum(acc)*(1.0f/64.0f);
    float dd=acc-mu;
    float var=wsum(dd*dd)*(1.0f/64.0f);
    float y=dd*(1.0f/sqrtf(var+1e-5f))*gv+bv2;
    a1[(nb+r)*64+lane]=fmaxf(y,0.0f);
    xrA=xrB; dAA=dBB;
    xsA0=xsB0; xsA1=xsB1; xsA2=xsB2;
    wA0=wB0; wA1=wB1; wA2=wB2;
  }
}

__global__ __launch_bounds__(256) void agg2_w2(const float* __restrict__ a1,
    const float* __restrict__ ew, const float* __restrict__ dis,
    const int* __restrict__ knn, const float* __restrict__ W2,
    const float* __restrict__ bb2, const float* __restrict__ x,
    float* __restrict__ out){
  __shared__ float rowbuf[4][64];
  int tid=threadIdx.x;
  int wave=tid>>6, lane=tid&63;
  float wcol[64];
  #pragma unroll
  for(int k=0;k<64;k++) wcol[k]=W2[k*64+lane];
  float bv=bb2[lane];
  int nb=blockIdx.x*16+wave*4;
  float xrA,dAA,xsA0,xsA1,xsA2,wA0,wA1,wA2;
  float xrB,dBB,xsB0,xsB1,xsB2,wB0,wB1,wB2;
  {
    int i=nb;
    float di=dis[i]; dAA=di*di;
    xrA=a1[i*64+lane];
    int s0=knn[i*3+0], s1=knn[i*3+1], s2=knn[i*3+2];
    xsA0=a1[s0*64+lane]; xsA1=a1[s1*64+lane]; xsA2=a1[s2*64+lane];
    wA0=dis[s0]*ew[i*3+0]*di; wA1=dis[s1]*ew[i*3+1]*di; wA2=dis[s2]*ew[i*3+2]*di;
  }
  #pragma unroll
  for(int r=0;r<4;r++){
    if(r<3){
      int i=nb+r+1;
      float di=dis[i]; dBB=di*di;
      xrB=a1[i*64+lane];
      int s0=knn[i*3+0], s1=knn[i*3+1], s2=knn[i*3+2];
      xsB0=a1[s0*64+lane]; xsB1=a1[s1*64+lane]; xsB2=a1[s2*64+lane];
      wB0=dis[s0]*ew[i*3+0]*di; wB1=dis[s1]*ew[i*3+1]*di; wB2=dis[s2]*ew[i*3+2]*di;
    }
    float aa=xrA*dAA;
    aa=fmaf(xsA0,wA0,aa); aa=fmaf(xsA1,wA1,aa); aa=fmaf(xsA2,wA2,aa);
    rowbuf[wave][lane]=aa;
    const float4* rb=(const float4*)&rowbuf[wave][0];
    float acc=0.f;
    #pragma unroll
    for(int k4=0;k4<16;k4++){
      float4 av=rb[k4];
      acc=fmaf(av.x,wcol[k4*4+0],acc);
      acc=fmaf(av.y,wcol[k4*4+1],acc);
      acc=fmaf(av.z,wcol[k4*4+2],acc);
      acc=fmaf(av.w,wcol[k4*4+3],acc);
    }
    acc+=bv;
    float xv=x[(nb+r)*64+lane];
    out[(nb+r)*64+lane]=(acc+xv)+xv;
    xrA=xrB; dAA=dBB;
    xsA0=xsB0; xsA1=xsB1; xsA2=xsB2;
    wA0=wB0; wA1=wB1; wA2=wB2;
  }
}

extern "C" void kernel_launch(void* const* d_in, const int* in_sizes, int n_in,
                              void* d_out, int out_size, void* d_ws, size_t ws_size,
                              hipStream_t stream){
  const float* feat  =(const float*)d_in[0];
  // d_in[1] edge_index_tran, d_in[2] edge_attr_rpe, d_in[3] norm_index: unused by reference
  const float* coords=(const float*)d_in[4];
  const float* g1 =(const float*)d_in[5];
  const float* b1n=(const float*)d_in[6];
  const float* g2 =(const float*)d_in[7];
  const float* b2n=(const float*)d_in[8];
  const float* gg =(const float*)d_in[9];
  const float* gb =(const float*)d_in[10];
  const float* W1 =(const float*)d_in[11];
  const float* bb1=(const float*)d_in[12];
  const float* W2 =(const float*)d_in[13];
  const float* bb2=(const float*)d_in[14];
  float* out=(float*)d_out;

  char* ws=(char*)d_ws;
  size_t o=0;
  float*  x      =(float*) (ws+o); o+=(size_t)N*64*4;
  float*  a1     =(float*) (ws+o); o+=(size_t)N*64*4;
  float*  xn     =(float*) (ws+o); o+=(size_t)N*4;
  float*  ew     =(float*) (ws+o); o+=(size_t)N*3*4;
  float*  dis    =(float*) (ws+o); o+=(size_t)N*4;
  int*    knn    =(int*)   (ws+o); o+=(size_t)N*3*4;
  float4* c4     =(float4*)(ws+o); o+=(size_t)N*16;
  float4* sc4    =(float4*)(ws+o); o+=(size_t)N*16;
  int*    sidx   =(int*)   (ws+o); o+=(size_t)N*4;
  int*    cellSt =(int*)   (ws+o); o+=(size_t)(NCELL+1)*4;
  o=(o+255)&~(size_t)255;
  int*    cnt    =(int*)   (ws+o); o+=(size_t)NCELL*4;   // fallback only
  int*    cursor =(int*)   (ws+o); o+=(size_t)NCELL*4;
  (void)ws_size; (void)in_sizes; (void)n_in; (void)out_size;

  Params Pm;
  Pm.feat=feat; Pm.coords=coords; Pm.g1=g1; Pm.b1=b1n; Pm.g2=g2; Pm.b2=b2n;
  Pm.gg=gg; Pm.gb=gb; Pm.W1=W1; Pm.bb1=bb1; Pm.W2=W2; Pm.bb2=bb2;
  Pm.out=out; Pm.x=x; Pm.a1=a1; Pm.xn=xn; Pm.ew=ew; Pm.dis=dis;
  Pm.knn=knn; Pm.c4=c4; Pm.sc4=sc4; Pm.sidx=sidx; Pm.cellSt=cellSt; Pm.cursor=cursor;
  void* args[] = { (void*)&Pm };

  hipError_t e = hipLaunchCooperativeKernel((const void*)fused, dim3(NBLK), dim3(NTHR),
                                            args, 0, stream);
  if(e != hipSuccess){
    (void)hipGetLastError();   // clear error state, use proven 6-dispatch path
    hipMemsetAsync((void*)cnt, 0, (size_t)2*NCELL*4, stream);
    hipLaunchKernelGGL(ln_kernel, dim3(N/4),   dim3(256), 0, stream, feat,g1,b1n,g2,b2n,coords,x,xn,c4,cnt);
    hipLaunchKernelGGL(scatter_k, dim3(N/256), dim3(256), 0, stream, c4,cnt,cursor,sc4,sidx,cellSt);
    hipLaunchKernelGGL(knn_ew,    dim3(2048),  dim3(256), 0, stream, sc4,sidx,cellSt,c4,x,xn,knn,ew,dis);
    hipLaunchKernelGGL(agg1_w1,   dim3(N/16),  dim3(256), 0, stream, x,ew,dis,knn,W1,bb1,gg,gb,a1);
    hipLaunchKernelGGL(agg2_w2,   dim3(N/16),  dim3(256), 0, stream, a1,ew,dis,knn,W2,bb2,x,out);
  }
}

// Round 3
// 157.026 us; speedup vs baseline: 3.1519x; 3.1519x over previous
//
#include <hip/hip_runtime.h>
#include <math.h>

#define N 16384
#define GC 8             // grid cells per dim (margin >= 1/8 -> fallback ~never fires)
#define NCELL (GC*GC*GC) // 512
#define NSCB (N/256)     // 64 scatter blocks (heterogeneous head of prep_ln grid)
#define NLNB (N/4)       // 4096 LN blocks

__device__ __forceinline__ float wsum(float v){
  #pragma unroll
  for(int m=32;m>0;m>>=1) v += __shfl_xor(v,m,64);
  return v;
}

// branchless lexicographic (d,idx) top-3 insert; matches jax top_k stable tie-break
__device__ __forceinline__ void lexins(float dd,int j2,
    float&D0,float&D1,float&D2,int&I0,int&I1,int&I2){
  bool lt0=(dd<D0)||((dd==D0)&&(j2<I0));
  bool lt1=(dd<D1)||((dd==D1)&&(j2<I1));
  bool lt2=(dd<D2)||((dd==D2)&&(j2<I2));
  float nD2=lt1?D1:(lt2?dd:D2); int nI2=lt1?I1:(lt2?j2:I2);
  float nD1=lt0?D0:(lt1?dd:D1); int nI1=lt0?I0:(lt1?j2:I1);
  float nD0=lt0?dd:D0;          int nI0=lt0?j2:I0;
  D0=nD0;D1=nD1;D2=nD2;I0=nI0;I1=nI1;I2=nI2;
}

// reference-exact squared distance: dd = rn(rn(qs+cs) - 2*dot), dot FMA chain
__device__ __forceinline__ float refdist(float qx,float qy,float qz,float qs,float4 cv){
  float dot=__fmaf_rn(qz,cv.z,__fmaf_rn(qy,cv.y,__fmul_rn(qx,cv.x)));
  float sc =__fadd_rn(qs,cv.w);
  return __fmaf_rn(-2.0f,dot,sc);
}

__device__ __forceinline__ int cellOf3(float a,float b,float c){
  int cx=min(GC-1,(int)(a*(float)GC)), cy=min(GC-1,(int)(b*(float)GC)),
      cz=min(GC-1,(int)(c*(float)GC));
  return (cz*GC+cy)*GC+cx;
}

// ---- K1 (heterogeneous): blocks [0,NSCB) = scatter role; rest = LN role. ----
// Scatter role is per-block self-contained: full histogram from coords in LDS
// (hist depends ONLY on coords, so it needs nothing from the LN role), local
// scan -> exclusive starts, then place own 256 points at
//   excl[cell] + (#points with idx < base in cell) + LDS-local cursor.
// Positions are disjoint+covering across blocks (index ranges partition N);
// within-cell order nondeterministic -- OK, knn top-3 tie-break is (d,idx).
// LN role: one wave per row, LN -> x2 -> LN, row norms. Unchanged math.
__global__ __launch_bounds__(256) void prep_ln(const float* __restrict__ in,
    const float* __restrict__ g1,const float* __restrict__ b1,
    const float* __restrict__ g2,const float* __restrict__ b2,
    const float* __restrict__ coords,
    float* __restrict__ x, float* __restrict__ xn, float4* __restrict__ c4,
    float4* __restrict__ sc4, int* __restrict__ sidx, int* __restrict__ cellSt){
  int tid=threadIdx.x, bid=blockIdx.x;
  if(bid<NSCB){
    __shared__ int A[NCELL];   // histogram, then reused as local cursor
    __shared__ int B[NCELL];   // prefix count (idx < base)
    __shared__ int C[NCELL];   // scan buffer -> exclusive starts
    A[tid]=0; A[tid+256]=0; B[tid]=0; B[tid+256]=0;
    __syncthreads();
    int base=bid*256;
    for(int i=tid;i<N;i+=256){
      float a=coords[i*3+0], b=coords[i*3+1], c=coords[i*3+2];
      int cell=cellOf3(a,b,c);
      atomicAdd(&A[cell],1);
      if(i<base) atomicAdd(&B[cell],1);
    }
    __syncthreads();
    C[tid]=A[tid]; C[tid+256]=A[tid+256];
    __syncthreads();
    for(int off=1;off<NCELL;off<<=1){
      int v0=(tid>=off)?C[tid-off]:0;
      int v1=((tid+256)>=off)?C[tid+256-off]:0;
      __syncthreads();
      C[tid]+=v0; C[tid+256]+=v1;
      __syncthreads();
    }
    C[tid]-=A[tid]; C[tid+256]-=A[tid+256];   // -> exclusive starts
    A[tid]=0; A[tid+256]=0;                   // reuse as local cursor
    __syncthreads();
    if(bid==0){
      cellSt[tid]=C[tid]; cellSt[tid+256]=C[tid+256];
      if(tid==0) cellSt[NCELL]=N;
    }
    int i=base+tid;
    float a=coords[i*3+0], b=coords[i*3+1], c=coords[i*3+2];
    float sq=__fadd_rn(__fadd_rn(__fmul_rn(a,a),__fmul_rn(b,b)),__fmul_rn(c,c));
    float4 v=make_float4(a,b,c,sq);
    int cell=cellOf3(a,b,c);
    int pos=C[cell]+B[cell]+atomicAdd(&A[cell],1);
    sc4[pos]=v; sidx[pos]=i; c4[i]=v;
  } else {
    int wave=tid>>6, lane=tid&63;
    int row=(bid-NSCB)*4+wave;
    float v=in[row*64+lane];
    float m=wsum(v)*(1.0f/64.0f);
    float d=v-m;
    float var=wsum(d*d)*(1.0f/64.0f);
    float y=d*(1.0f/sqrtf(var+1e-5f))*g1[lane]+b1[lane];
    y=y+y;  // transformer stubbed as identity + shortcut
    float m2=wsum(y)*(1.0f/64.0f);
    float d2=y-m2;
    float var2=wsum(d2*d2)*(1.0f/64.0f);
    float z=d2*(1.0f/sqrtf(var2+1e-5f))*g2[lane]+b2[lane];
    x[row*64+lane]=z;
    float s=wsum(z*z);
    if(lane==0) xn[row]=fmaxf(sqrtf(s),1e-8f);
  }
}

// ---- K2: grid KNN (32 lanes/query, pruned cell runs) + edge weights. ----
// 2048 blocks x 256 (full occupancy -- R2 lesson: never starve this of TLP).
// Runs ordered center -> faces -> diagonals; a run is skipped iff its
// geometric lower bound exceeds current D2 plus conservative slack. The
// whole-region margin check + fallback certifies exactness.
__global__ __launch_bounds__(256) void knn_ew(const float4* __restrict__ sc4,
    const int* __restrict__ sidx, const int* __restrict__ cellSt,
    const float4* __restrict__ c4, const float* __restrict__ x,
    const float* __restrict__ xn,
    int* __restrict__ knn, float* __restrict__ ew, float* __restrict__ dis){
  int tid=threadIdx.x, bid=blockIdx.x;
  int gt=bid*256+tid;
  int lane=tid&63;
  int slot=gt>>5, part=tid&31;
  float4 qv=sc4[slot]; int q=sidx[slot];
  float qx=qv.x,qy=qv.y,qz=qv.z,qs=qv.w;
  int cx=min(GC-1,(int)(qx*(float)GC)), cy=min(GC-1,(int)(qy*(float)GC)),
      cz=min(GC-1,(int)(qz*(float)GC));
  float D0=1e30f,D1=1e30f,D2=1e30f; int I0=0x7fffffff,I1=0x7fffffff,I2=0x7fffffff;
  int xlo=max(cx-1,0), xhi=min(cx+1,GC-1);
  const float cw=1.0f/(float)GC;
  float fy0=qy-(float)cy*cw, fy1=(float)(cy+1)*cw-qy;   // dist to y faces
  float fz0=qz-(float)cz*cw, fz1=(float)(cz+1)*cw-qz;   // dist to z faces
  const int OY[9]={0,-1,1, 0,0,-1, 1,-1,1};
  const int OZ[9]={0, 0,0,-1,1,-1,-1, 1,1};
  #pragma unroll 1
  for(int k=0;k<9;k++){
    int oy=OY[k], oz=OZ[k];
    int y2=cy+oy, z2=cz+oz;
    if(y2<0||y2>=GC||z2<0||z2>=GC) continue;
    if(k>0){
      float dy=(oy<0)?fy0:((oy>0)?fy1:0.0f);
      float dz=(oz<0)?fz0:((oz>0)?fz1:0.0f);
      float bnd=dy*dy+dz*dz;
      if(bnd>D2+1e-5f) continue;          // conservative skip
    }
    int rowb=(z2*GC+y2)*GC;
    int p0=cellSt[rowb+xlo], p1=cellSt[rowb+xhi+1];  // x-cells contiguous
    for(int p=p0+part;p<p1;p+=32){
      float4 cv=sc4[p]; int j2=sidx[p];
      float dd=refdist(qx,qy,qz,qs,cv);
      dd=(j2==q)?1e30f:dd;
      lexins(dd,j2,D0,D1,D2,I0,I1,I2);
    }
  }
  #pragma unroll
  for(int m=1;m<32;m<<=1){
    float e0=__shfl_xor(D0,m),e1=__shfl_xor(D1,m),e2=__shfl_xor(D2,m);
    int   f0=__shfl_xor(I0,m),f1=__shfl_xor(I1,m),f2=__shfl_xor(I2,m);
    lexins(e0,f0,D0,D1,D2,I0,I1,I2);
    lexins(e1,f1,D0,D1,D2,I0,I1,I2);
    lexins(e2,f2,D0,D1,D2,I0,I1,I2);
  }
  bool flg=false;
  if(part==0){
    float mg=1e30f;
    mg=fminf(mg,(cx>0)?(qx-(float)(cx-1)*cw):1e30f);
    mg=fminf(mg,(cx<GC-1)?((float)(cx+2)*cw-qx):1e30f);
    mg=fminf(mg,(cy>0)?(qy-(float)(cy-1)*cw):1e30f);
    mg=fminf(mg,(cy<GC-1)?((float)(cy+2)*cw-qy):1e30f);
    mg=fminf(mg,(cz>0)?(qz-(float)(cz-1)*cw):1e30f);
    mg=fminf(mg,(cz<GC-1)?((float)(cz+2)*cw-qz):1e30f);
    float mg2=mg*mg*(1.0f-1e-5f);   // slack for dd rounding
    flg=!(D2<mg2);                  // at GC=8: ~never true
  }
  unsigned long long mask=__ballot(flg);
  while(mask){
    int b=__ffsll((unsigned long long)mask)-1; mask&=mask-1;
    int qb=__shfl(q,b);
    float bx=__shfl(qx,b),by=__shfl(qy,b),bz=__shfl(qz,b),bs=__shfl(qs,b);
    float E0=1e30f,E1=1e30f,E2=1e30f; int F0=0x7fffffff,F1=0x7fffffff,F2=0x7fffffff;
    for(int j=lane;j<N;j+=64){
      float4 cv=c4[j];
      float dd=refdist(bx,by,bz,bs,cv);
      dd=(j==qb)?1e30f:dd;
      lexins(dd,j,E0,E1,E2,F0,F1,F2);
    }
    #pragma unroll
    for(int m=1;m<64;m<<=1){
      float e0=__shfl_xor(E0,m),e1=__shfl_xor(E1,m),e2=__shfl_xor(E2,m);
      int   f0=__shfl_xor(F0,m),f1=__shfl_xor(F1,m),f2=__shfl_xor(F2,m);
      lexins(e0,f0,E0,E1,E2,F0,F1,F2);
      lexins(e1,f1,E0,E1,E2,F0,F1,F2);
      lexins(e2,f2,E0,E1,E2,F0,F1,F2);
    }
    if(lane==b){ I0=F0; I1=F1; I2=F2; }
  }
  if(part==0){ knn[q*3+0]=I0; knn[q*3+1]=I1; knn[q*3+2]=I2; }
  // --- ew + dis for the wave's 2 queries (neighbor loads hoisted) ---
  for(int r=0;r<2;r++){
    int qi=__shfl(q,32*r);
    int s0=__shfl(I0,32*r), s1=__shfl(I1,32*r), s2=__shfl(I2,32*r);
    float xi=x[qi*64+lane];
    float xs0=x[s0*64+lane], xs1=x[s1*64+lane], xs2=x[s2*64+lane];
    float n0=xn[s0], n1=xn[s1], n2=xn[s2];
    float ni=xn[qi];
    float dt0=wsum(xs0*xi), dt1=wsum(xs1*xi), dt2=wsum(xs2*xi);
    float e0=1.f/(1.f+expf(-(dt0/(n0*ni))));
    float e1=1.f/(1.f+expf(-(dt1/(n1*ni))));
    float e2=1.f/(1.f+expf(-(dt2/(n2*ni))));
    if(lane==0){
      ew[qi*3+0]=e0; ew[qi*3+1]=e1; ew[qi*3+2]=e2;
      float ssum=((e0+e1)+e2);
      dis[qi]=1.f/sqrtf(ssum+1.0f);             // deg = 1 (self loop) + sum(ew)
    }
  }
}

// ---- K3: xa = weighted-agg(x); a1 = relu(LN(xa@W1 + b1)). Wave per 4 nodes. ----
// W column in 64 VGPRs/lane; 2-deep pipeline hides knn->gather chain.
__global__ __launch_bounds__(256) void agg1_w1(const float* __restrict__ x,
    const float* __restrict__ ew, const float* __restrict__ dis,
    const int* __restrict__ knn, const float* __restrict__ W1,
    const float* __restrict__ bb1, const float* __restrict__ gg,
    const float* __restrict__ gb, float* __restrict__ a1){
  __shared__ float rowbuf[4][64];
  int tid=threadIdx.x;
  int wave=tid>>6, lane=tid&63;
  float wcol[64];
  #pragma unroll
  for(int k=0;k<64;k++) wcol[k]=W1[k*64+lane];   // coalesced, L2-hit
  float bv=bb1[lane], gv=gg[lane], bv2=gb[lane];
  int nb=blockIdx.x*16+wave*4;
  float xrA,dAA,xsA0,xsA1,xsA2,wA0,wA1,wA2;
  float xrB,dBB,xsB0,xsB1,xsB2,wB0,wB1,wB2;
  {
    int i=nb;
    float di=dis[i]; dAA=di*di;
    xrA=x[i*64+lane];
    int s0=knn[i*3+0], s1=knn[i*3+1], s2=knn[i*3+2];
    xsA0=x[s0*64+lane]; xsA1=x[s1*64+lane]; xsA2=x[s2*64+lane];
    wA0=dis[s0]*ew[i*3+0]*di; wA1=dis[s1]*ew[i*3+1]*di; wA2=dis[s2]*ew[i*3+2]*di;
  }
  #pragma unroll
  for(int r=0;r<4;r++){
    if(r<3){
      int i=nb+r+1;
      float di=dis[i]; dBB=di*di;
      xrB=x[i*64+lane];
      int s0=knn[i*3+0], s1=knn[i*3+1], s2=knn[i*3+2];
      xsB0=x[s0*64+lane]; xsB1=x[s1*64+lane]; xsB2=x[s2*64+lane];
      wB0=dis[s0]*ew[i*3+0]*di; wB1=dis[s1]*ew[i*3+1]*di; wB2=dis[s2]*ew[i*3+2]*di;
    }
    float xa=xrA*dAA;
    xa=fmaf(xsA0,wA0,xa); xa=fmaf(xsA1,wA1,xa); xa=fmaf(xsA2,wA2,xa);
    rowbuf[wave][lane]=xa;
    const float4* rb=(const float4*)&rowbuf[wave][0];
    float acc=0.f;
    #pragma unroll
    for(int k4=0;k4<16;k4++){
      float4 av=rb[k4];
      acc=fmaf(av.x,wcol[k4*4+0],acc);
      acc=fmaf(av.y,wcol[k4*4+1],acc);
      acc=fmaf(av.z,wcol[k4*4+2],acc);
      acc=fmaf(av.w,wcol[k4*4+3],acc);
    }
    acc+=bv;
    float mu=wsum(acc)*(1.0f/64.0f);
    float dd=acc-mu;
    float var=wsum(dd*dd)*(1.0f/64.0f);
    float y=dd*(1.0f/sqrtf(var+1e-5f))*gv+bv2;
    a1[(nb+r)*64+lane]=fmaxf(y,0.0f);
    xrA=xrB; dAA=dBB;
    xsA0=xsB0; xsA1=xsB1; xsA2=xsB2;
    wA0=wB0; wA1=wB1; wA2=wB2;
  }
}

// ---- K4: aa = weighted-agg(a1); out = aa@W2 + b2 + 2x. Wave per 4 nodes. ----
__global__ __launch_bounds__(256) void agg2_w2(const float* __restrict__ a1,
    const float* __restrict__ ew, const float* __restrict__ dis,
    const int* __restrict__ knn, const float* __restrict__ W2,
    const float* __restrict__ bb2, const float* __restrict__ x,
    float* __restrict__ out){
  __shared__ float rowbuf[4][64];
  int tid=threadIdx.x;
  int wave=tid>>6, lane=tid&63;
  float wcol[64];
  #pragma unroll
  for(int k=0;k<64;k++) wcol[k]=W2[k*64+lane];
  float bv=bb2[lane];
  int nb=blockIdx.x*16+wave*4;
  float xrA,dAA,xsA0,xsA1,xsA2,wA0,wA1,wA2;
  float xrB,dBB,xsB0,xsB1,xsB2,wB0,wB1,wB2;
  {
    int i=nb;
    float di=dis[i]; dAA=di*di;
    xrA=a1[i*64+lane];
    int s0=knn[i*3+0], s1=knn[i*3+1], s2=knn[i*3+2];
    xsA0=a1[s0*64+lane]; xsA1=a1[s1*64+lane]; xsA2=a1[s2*64+lane];
    wA0=dis[s0]*ew[i*3+0]*di; wA1=dis[s1]*ew[i*3+1]*di; wA2=dis[s2]*ew[i*3+2]*di;
  }
  #pragma unroll
  for(int r=0;r<4;r++){
    if(r<3){
      int i=nb+r+1;
      float di=dis[i]; dBB=di*di;
      xrB=a1[i*64+lane];
      int s0=knn[i*3+0], s1=knn[i*3+1], s2=knn[i*3+2];
      xsB0=a1[s0*64+lane]; xsB1=a1[s1*64+lane]; xsB2=a1[s2*64+lane];
      wB0=dis[s0]*ew[i*3+0]*di; wB1=dis[s1]*ew[i*3+1]*di; wB2=dis[s2]*ew[i*3+2]*di;
    }
    float aa=xrA*dAA;
    aa=fmaf(xsA0,wA0,aa); aa=fmaf(xsA1,wA1,aa); aa=fmaf(xsA2,wA2,aa);
    rowbuf[wave][lane]=aa;
    const float4* rb=(const float4*)&rowbuf[wave][0];
    float acc=0.f;
    #pragma unroll
    for(int k4=0;k4<16;k4++){
      float4 av=rb[k4];
      acc=fmaf(av.x,wcol[k4*4+0],acc);
      acc=fmaf(av.y,wcol[k4*4+1],acc);
      acc=fmaf(av.z,wcol[k4*4+2],acc);
      acc=fmaf(av.w,wcol[k4*4+3],acc);
    }
    acc+=bv;
    float xv=x[(nb+r)*64+lane];
    out[(nb+r)*64+lane]=(acc+xv)+xv;  // (gcn2 + x) + shortcut, shortcut == x
    xrA=xrB; dAA=dBB;
    xsA0=xsB0; xsA1=xsB1; xsA2=xsB2;
    wA0=wB0; wA1=wB1; wA2=wB2;
  }
}

extern "C" void kernel_launch(void* const* d_in, const int* in_sizes, int n_in,
                              void* d_out, int out_size, void* d_ws, size_t ws_size,
                              hipStream_t stream){
  const float* feat  =(const float*)d_in[0];
  // d_in[1] edge_index_tran, d_in[2] edge_attr_rpe, d_in[3] norm_index: unused by reference
  const float* coords=(const float*)d_in[4];
  const float* g1 =(const float*)d_in[5];
  const float* b1n=(const float*)d_in[6];
  const float* g2 =(const float*)d_in[7];
  const float* b2n=(const float*)d_in[8];
  const float* gg =(const float*)d_in[9];
  const float* gb =(const float*)d_in[10];
  const float* W1 =(const float*)d_in[11];
  const float* bb1=(const float*)d_in[12];
  const float* W2 =(const float*)d_in[13];
  const float* bb2=(const float*)d_in[14];
  float* out=(float*)d_out;

  char* ws=(char*)d_ws;
  size_t o=0;
  float*  x      =(float*) (ws+o); o+=(size_t)N*64*4;    // post-LN2 features
  float*  a1     =(float*) (ws+o); o+=(size_t)N*64*4;    // activated GCN1 output
  float*  xn     =(float*) (ws+o); o+=(size_t)N*4;       // row norms of x
  float*  ew     =(float*) (ws+o); o+=(size_t)N*3*4;     // knn edge weights
  float*  dis    =(float*) (ws+o); o+=(size_t)N*4;       // 1/sqrt(deg)
  int*    knn    =(int*)   (ws+o); o+=(size_t)N*3*4;     // neighbor indices
  float4* c4     =(float4*)(ws+o); o+=(size_t)N*16;      // (x,y,z,sq) original order
  float4* sc4    =(float4*)(ws+o); o+=(size_t)N*16;      // cell-sorted
  int*    sidx   =(int*)   (ws+o); o+=(size_t)N*4;       // sorted -> original
  int*    cellSt =(int*)   (ws+o); o+=(size_t)(NCELL+1)*4;
  (void)ws_size; (void)in_sizes; (void)n_in; (void)out_size;

  hipLaunchKernelGGL(prep_ln, dim3(NSCB+NLNB), dim3(256), 0, stream,
                     feat,g1,b1n,g2,b2n,coords,x,xn,c4,sc4,sidx,cellSt);
  hipLaunchKernelGGL(knn_ew,  dim3(2048),      dim3(256), 0, stream,
                     sc4,sidx,cellSt,c4,x,xn,knn,ew,dis);
  hipLaunchKernelGGL(agg1_w1, dim3(N/16),      dim3(256), 0, stream,
                     x,ew,dis,knn,W1,bb1,gg,gb,a1);
  hipLaunchKernelGGL(agg2_w2, dim3(N/16),      dim3(256), 0, stream,
                     a1,ew,dis,knn,W2,bb2,x,out);
}

// Round 4
// 154.513 us; speedup vs baseline: 3.2032x; 1.0163x over previous
//
#include <hip/hip_runtime.h>
#include <math.h>

#define N 16384
#define GC 8             // grid cells per dim (margin >= 1/8 -> fallback ~never fires)
#define NCELL (GC*GC*GC) // 512
#define NSCB (N/256)     // 64 scatter blocks (heterogeneous head of prep_ln grid)
#define NLNB (N/4)       // 4096 LN blocks

__device__ __forceinline__ float wsum(float v){
  #pragma unroll
  for(int m=32;m>0;m>>=1) v += __shfl_xor(v,m,64);
  return v;
}

// lane-k broadcast via v_readlane (constant k) -> SGPR, fma takes 1 SGPR operand
__device__ __forceinline__ float rl(float v,int k){
  return __int_as_float(__builtin_amdgcn_readlane(__float_as_int(v),k));
}

// branchless lexicographic (d,idx) top-3 insert; matches jax top_k stable tie-break
__device__ __forceinline__ void lexins(float dd,int j2,
    float&D0,float&D1,float&D2,int&I0,int&I1,int&I2){
  bool lt0=(dd<D0)||((dd==D0)&&(j2<I0));
  bool lt1=(dd<D1)||((dd==D1)&&(j2<I1));
  bool lt2=(dd<D2)||((dd==D2)&&(j2<I2));
  float nD2=lt1?D1:(lt2?dd:D2); int nI2=lt1?I1:(lt2?j2:I2);
  float nD1=lt0?D0:(lt1?dd:D1); int nI1=lt0?I0:(lt1?j2:I1);
  float nD0=lt0?dd:D0;          int nI0=lt0?j2:I0;
  D0=nD0;D1=nD1;D2=nD2;I0=nI0;I1=nI1;I2=nI2;
}

// reference-exact squared distance: dd = rn(rn(qs+cs) - 2*dot), dot FMA chain
__device__ __forceinline__ float refdist(float qx,float qy,float qz,float qs,float4 cv){
  float dot=__fmaf_rn(qz,cv.z,__fmaf_rn(qy,cv.y,__fmul_rn(qx,cv.x)));
  float sc =__fadd_rn(qs,cv.w);
  return __fmaf_rn(-2.0f,dot,sc);
}

__device__ __forceinline__ int cellOf3(float a,float b,float c){
  int cx=min(GC-1,(int)(a*(float)GC)), cy=min(GC-1,(int)(b*(float)GC)),
      cz=min(GC-1,(int)(c*(float)GC));
  return (cz*GC+cy)*GC+cx;
}

// ---- K1 (heterogeneous): blocks [0,NSCB) = scatter role; rest = LN role. ----
// Scatter role per-block self-contained (histogram from coords only, local scan,
// place own 256 points at excl[cell] + prefix<base + local cursor). Positions
// disjoint+covering; within-cell order nondeterministic -- OK, top-3 tie-break
// is lexicographic (d,idx). LN role: one wave per row. Unchanged math.
__global__ __launch_bounds__(256) void prep_ln(const float* __restrict__ in,
    const float* __restrict__ g1,const float* __restrict__ b1,
    const float* __restrict__ g2,const float* __restrict__ b2,
    const float* __restrict__ coords,
    float* __restrict__ x, float* __restrict__ xn, float4* __restrict__ c4,
    float4* __restrict__ sc4, int* __restrict__ sidx, int* __restrict__ cellSt){
  int tid=threadIdx.x, bid=blockIdx.x;
  if(bid<NSCB){
    __shared__ int A[NCELL];   // histogram, then reused as local cursor
    __shared__ int B[NCELL];   // prefix count (idx < base)
    __shared__ int C[NCELL];   // scan buffer -> exclusive starts
    A[tid]=0; A[tid+256]=0; B[tid]=0; B[tid+256]=0;
    __syncthreads();
    int base=bid*256;
    for(int i=tid;i<N;i+=256){
      float a=coords[i*3+0], b=coords[i*3+1], c=coords[i*3+2];
      int cell=cellOf3(a,b,c);
      atomicAdd(&A[cell],1);
      if(i<base) atomicAdd(&B[cell],1);
    }
    __syncthreads();
    C[tid]=A[tid]; C[tid+256]=A[tid+256];
    __syncthreads();
    for(int off=1;off<NCELL;off<<=1){
      int v0=(tid>=off)?C[tid-off]:0;
      int v1=((tid+256)>=off)?C[tid+256-off]:0;
      __syncthreads();
      C[tid]+=v0; C[tid+256]+=v1;
      __syncthreads();
    }
    C[tid]-=A[tid]; C[tid+256]-=A[tid+256];   // -> exclusive starts
    A[tid]=0; A[tid+256]=0;                   // reuse as local cursor
    __syncthreads();
    if(bid==0){
      cellSt[tid]=C[tid]; cellSt[tid+256]=C[tid+256];
      if(tid==0) cellSt[NCELL]=N;
    }
    int i=base+tid;
    float a=coords[i*3+0], b=coords[i*3+1], c=coords[i*3+2];
    float sq=__fadd_rn(__fadd_rn(__fmul_rn(a,a),__fmul_rn(b,b)),__fmul_rn(c,c));
    float4 v=make_float4(a,b,c,sq);
    int cell=cellOf3(a,b,c);
    int pos=C[cell]+B[cell]+atomicAdd(&A[cell],1);
    sc4[pos]=v; sidx[pos]=i; c4[i]=v;
  } else {
    int wave=tid>>6, lane=tid&63;
    int row=(bid-NSCB)*4+wave;
    float v=in[row*64+lane];
    float m=wsum(v)*(1.0f/64.0f);
    float d=v-m;
    float var=wsum(d*d)*(1.0f/64.0f);
    float y=d*(1.0f/sqrtf(var+1e-5f))*g1[lane]+b1[lane];
    y=y+y;  // transformer stubbed as identity + shortcut
    float m2=wsum(y)*(1.0f/64.0f);
    float d2=y-m2;
    float var2=wsum(d2*d2)*(1.0f/64.0f);
    float z=d2*(1.0f/sqrtf(var2+1e-5f))*g2[lane]+b2[lane];
    x[row*64+lane]=z;
    float s=wsum(z*z);
    if(lane==0) xn[row]=fmaxf(sqrtf(s),1e-8f);
  }
}

// ---- K2: grid KNN (32 lanes/query, pruned cell runs) + edge weights. ----
// 2048 blocks x 256 (full occupancy). Hot-loop insert is exec-masked: lexins
// is identity when the point doesn't beat (D2,I2), so skipping non-inserting
// lanes is semantics-preserving; s_cbranch_execz skips the 12-inst body when
// no lane in the wave inserts (common late in the scan).
__global__ __launch_bounds__(256) void knn_ew(const float4* __restrict__ sc4,
    const int* __restrict__ sidx, const int* __restrict__ cellSt,
    const float4* __restrict__ c4, const float* __restrict__ x,
    const float* __restrict__ xn,
    int* __restrict__ knn, float* __restrict__ ew, float* __restrict__ dis){
  int tid=threadIdx.x, bid=blockIdx.x;
  int gt=bid*256+tid;
  int lane=tid&63;
  int slot=gt>>5, part=tid&31;
  float4 qv=sc4[slot]; int q=sidx[slot];
  float qx=qv.x,qy=qv.y,qz=qv.z,qs=qv.w;
  int cx=min(GC-1,(int)(qx*(float)GC)), cy=min(GC-1,(int)(qy*(float)GC)),
      cz=min(GC-1,(int)(qz*(float)GC));
  float D0=1e30f,D1=1e30f,D2=1e30f; int I0=0x7fffffff,I1=0x7fffffff,I2=0x7fffffff;
  int xlo=max(cx-1,0), xhi=min(cx+1,GC-1);
  const float cw=1.0f/(float)GC;
  float fy0=qy-(float)cy*cw, fy1=(float)(cy+1)*cw-qy;   // dist to y faces
  float fz0=qz-(float)cz*cw, fz1=(float)(cz+1)*cw-qz;   // dist to z faces
  const int OY[9]={0,-1,1, 0,0,-1, 1,-1,1};
  const int OZ[9]={0, 0,0,-1,1,-1,-1, 1,1};
  #pragma unroll 1
  for(int k=0;k<9;k++){
    int oy=OY[k], oz=OZ[k];
    int y2=cy+oy, z2=cz+oz;
    if(y2<0||y2>=GC||z2<0||z2>=GC) continue;
    if(k>0){
      float dy=(oy<0)?fy0:((oy>0)?fy1:0.0f);
      float dz=(oz<0)?fz0:((oz>0)?fz1:0.0f);
      float bnd=dy*dy+dz*dz;
      if(bnd>D2+1e-5f) continue;          // conservative skip
    }
    int rowb=(z2*GC+y2)*GC;
    int p0=cellSt[rowb+xlo], p1=cellSt[rowb+xhi+1];  // x-cells contiguous
    for(int p=p0+part;p<p1;p+=32){
      float4 cv=sc4[p]; int j2=sidx[p];
      float dd=refdist(qx,qy,qz,qs,cv);
      dd=(j2==q)?1e30f:dd;
      bool ins=(dd<D2)||((dd==D2)&&(j2<I2));
      if(ins) lexins(dd,j2,D0,D1,D2,I0,I1,I2);
    }
  }
  #pragma unroll
  for(int m=1;m<32;m<<=1){
    float e0=__shfl_xor(D0,m),e1=__shfl_xor(D1,m),e2=__shfl_xor(D2,m);
    int   f0=__shfl_xor(I0,m),f1=__shfl_xor(I1,m),f2=__shfl_xor(I2,m);
    lexins(e0,f0,D0,D1,D2,I0,I1,I2);
    lexins(e1,f1,D0,D1,D2,I0,I1,I2);
    lexins(e2,f2,D0,D1,D2,I0,I1,I2);
  }
  bool flg=false;
  if(part==0){
    float mg=1e30f;
    mg=fminf(mg,(cx>0)?(qx-(float)(cx-1)*cw):1e30f);
    mg=fminf(mg,(cx<GC-1)?((float)(cx+2)*cw-qx):1e30f);
    mg=fminf(mg,(cy>0)?(qy-(float)(cy-1)*cw):1e30f);
    mg=fminf(mg,(cy<GC-1)?((float)(cy+2)*cw-qy):1e30f);
    mg=fminf(mg,(cz>0)?(qz-(float)(cz-1)*cw):1e30f);
    mg=fminf(mg,(cz<GC-1)?((float)(cz+2)*cw-qz):1e30f);
    float mg2=mg*mg*(1.0f-1e-5f);   // slack for dd rounding
    flg=!(D2<mg2);                  // at GC=8: ~never true
  }
  unsigned long long mask=__ballot(flg);
  while(mask){
    int b=__ffsll((unsigned long long)mask)-1; mask&=mask-1;
    int qb=__shfl(q,b);
    float bx=__shfl(qx,b),by=__shfl(qy,b),bz=__shfl(qz,b),bs=__shfl(qs,b);
    float E0=1e30f,E1=1e30f,E2=1e30f; int F0=0x7fffffff,F1=0x7fffffff,F2=0x7fffffff;
    for(int j=lane;j<N;j+=64){
      float4 cv=c4[j];
      float dd=refdist(bx,by,bz,bs,cv);
      dd=(j==qb)?1e30f:dd;
      lexins(dd,j,E0,E1,E2,F0,F1,F2);
    }
    #pragma unroll
    for(int m=1;m<64;m<<=1){
      float e0=__shfl_xor(E0,m),e1=__shfl_xor(E1,m),e2=__shfl_xor(E2,m);
      int   f0=__shfl_xor(F0,m),f1=__shfl_xor(F1,m),f2=__shfl_xor(F2,m);
      lexins(e0,f0,E0,E1,E2,F0,F1,F2);
      lexins(e1,f1,E0,E1,E2,F0,F1,F2);
      lexins(e2,f2,E0,E1,E2,F0,F1,F2);
    }
    if(lane==b){ I0=F0; I1=F1; I2=F2; }
  }
  if(part==0){ knn[q*3+0]=I0; knn[q*3+1]=I1; knn[q*3+2]=I2; }
  // --- ew + dis for the wave's 2 queries (neighbor loads hoisted) ---
  for(int r=0;r<2;r++){
    int qi=__shfl(q,32*r);
    int s0=__shfl(I0,32*r), s1=__shfl(I1,32*r), s2=__shfl(I2,32*r);
    float xi=x[qi*64+lane];
    float xs0=x[s0*64+lane], xs1=x[s1*64+lane], xs2=x[s2*64+lane];
    float n0=xn[s0], n1=xn[s1], n2=xn[s2];
    float ni=xn[qi];
    float dt0=wsum(xs0*xi), dt1=wsum(xs1*xi), dt2=wsum(xs2*xi);
    float e0=1.f/(1.f+expf(-(dt0/(n0*ni))));
    float e1=1.f/(1.f+expf(-(dt1/(n1*ni))));
    float e2=1.f/(1.f+expf(-(dt2/(n2*ni))));
    if(lane==0){
      ew[qi*3+0]=e0; ew[qi*3+1]=e1; ew[qi*3+2]=e2;
      float ssum=((e0+e1)+e2);
      dis[qi]=1.f/sqrtf(ssum+1.0f);             // deg = 1 (self loop) + sum(ew)
    }
  }
}

// ---- K3: xa = weighted-agg(x); a1 = relu(LN(xa@W1 + b1)). Wave per 4 nodes. ----
// Matvec via v_readlane SGPR broadcast (no LDS): lane k holds xa[k]; unrolled
// constant-lane readlane feeds v_fma with one SGPR operand. Same k-ascending
// single FMA chain as before -> bitwise-identical result. 2-deep pipeline
// hides the knn->gather chain.
__global__ __launch_bounds__(256) void agg1_w1(const float* __restrict__ x,
    const float* __restrict__ ew, const float* __restrict__ dis,
    const int* __restrict__ knn, const float* __restrict__ W1,
    const float* __restrict__ bb1, const float* __restrict__ gg,
    const float* __restrict__ gb, float* __restrict__ a1){
  int tid=threadIdx.x;
  int wave=tid>>6, lane=tid&63;
  float wcol[64];
  #pragma unroll
  for(int k=0;k<64;k++) wcol[k]=W1[k*64+lane];   // coalesced, L2-hit
  float bv=bb1[lane], gv=gg[lane], bv2=gb[lane];
  int nb=blockIdx.x*16+wave*4;
  float xrA,dAA,xsA0,xsA1,xsA2,wA0,wA1,wA2;
  float xrB,dBB,xsB0,xsB1,xsB2,wB0,wB1,wB2;
  {
    int i=nb;
    float di=dis[i]; dAA=di*di;
    xrA=x[i*64+lane];
    int s0=knn[i*3+0], s1=knn[i*3+1], s2=knn[i*3+2];
    xsA0=x[s0*64+lane]; xsA1=x[s1*64+lane]; xsA2=x[s2*64+lane];
    wA0=dis[s0]*ew[i*3+0]*di; wA1=dis[s1]*ew[i*3+1]*di; wA2=dis[s2]*ew[i*3+2]*di;
  }
  #pragma unroll
  for(int r=0;r<4;r++){
    if(r<3){
      int i=nb+r+1;
      float di=dis[i]; dBB=di*di;
      xrB=x[i*64+lane];
      int s0=knn[i*3+0], s1=knn[i*3+1], s2=knn[i*3+2];
      xsB0=x[s0*64+lane]; xsB1=x[s1*64+lane]; xsB2=x[s2*64+lane];
      wB0=dis[s0]*ew[i*3+0]*di; wB1=dis[s1]*ew[i*3+1]*di; wB2=dis[s2]*ew[i*3+2]*di;
    }
    float xa=xrA*dAA;
    xa=fmaf(xsA0,wA0,xa); xa=fmaf(xsA1,wA1,xa); xa=fmaf(xsA2,wA2,xa);
    float acc=0.f;
    #pragma unroll
    for(int k=0;k<64;k++) acc=fmaf(rl(xa,k),wcol[k],acc);
    acc+=bv;
    float mu=wsum(acc)*(1.0f/64.0f);
    float dd=acc-mu;
    float var=wsum(dd*dd)*(1.0f/64.0f);
    float y=dd*(1.0f/sqrtf(var+1e-5f))*gv+bv2;
    a1[(nb+r)*64+lane]=fmaxf(y,0.0f);
    xrA=xrB; dAA=dBB;
    xsA0=xsB0; xsA1=xsB1; xsA2=xsB2;
    wA0=wB0; wA1=wB1; wA2=wB2;
  }
}

// ---- K4: aa = weighted-agg(a1); out = aa@W2 + b2 + 2x. Wave per 4 nodes. ----
__global__ __launch_bounds__(256) void agg2_w2(const float* __restrict__ a1,
    const float* __restrict__ ew, const float* __restrict__ dis,
    const int* __restrict__ knn, const float* __restrict__ W2,
    const float* __restrict__ bb2, const float* __restrict__ x,
    float* __restrict__ out){
  int tid=threadIdx.x;
  int wave=tid>>6, lane=tid&63;
  float wcol[64];
  #pragma unroll
  for(int k=0;k<64;k++) wcol[k]=W2[k*64+lane];
  float bv=bb2[lane];
  int nb=blockIdx.x*16+wave*4;
  float xrA,dAA,xsA0,xsA1,xsA2,wA0,wA1,wA2;
  float xrB,dBB,xsB0,xsB1,xsB2,wB0,wB1,wB2;
  {
    int i=nb;
    float di=dis[i]; dAA=di*di;
    xrA=a1[i*64+lane];
    int s0=knn[i*3+0], s1=knn[i*3+1], s2=knn[i*3+2];
    xsA0=a1[s0*64+lane]; xsA1=a1[s1*64+lane]; xsA2=a1[s2*64+lane];
    wA0=dis[s0]*ew[i*3+0]*di; wA1=dis[s1]*ew[i*3+1]*di; wA2=dis[s2]*ew[i*3+2]*di;
  }
  #pragma unroll
  for(int r=0;r<4;r++){
    if(r<3){
      int i=nb+r+1;
      float di=dis[i]; dBB=di*di;
      xrB=a1[i*64+lane];
      int s0=knn[i*3+0], s1=knn[i*3+1], s2=knn[i*3+2];
      xsB0=a1[s0*64+lane]; xsB1=a1[s1*64+lane]; xsB2=a1[s2*64+lane];
      wB0=dis[s0]*ew[i*3+0]*di; wB1=dis[s1]*ew[i*3+1]*di; wB2=dis[s2]*ew[i*3+2]*di;
    }
    float aa=xrA*dAA;
    aa=fmaf(xsA0,wA0,aa); aa=fmaf(xsA1,wA1,aa); aa=fmaf(xsA2,wA2,aa);
    float acc=0.f;
    #pragma unroll
    for(int k=0;k<64;k++) acc=fmaf(rl(aa,k),wcol[k],acc);
    acc+=bv;
    float xv=x[(nb+r)*64+lane];
    out[(nb+r)*64+lane]=(acc+xv)+xv;  // (gcn2 + x) + shortcut, shortcut == x
    xrA=xrB; dAA=dBB;
    xsA0=xsB0; xsA1=xsB1; xsA2=xsB2;
    wA0=wB0; wA1=wB1; wA2=wB2;
  }
}

extern "C" void kernel_launch(void* const* d_in, const int* in_sizes, int n_in,
                              void* d_out, int out_size, void* d_ws, size_t ws_size,
                              hipStream_t stream){
  const float* feat  =(const float*)d_in[0];
  // d_in[1] edge_index_tran, d_in[2] edge_attr_rpe, d_in[3] norm_index: unused by reference
  const float* coords=(const float*)d_in[4];
  const float* g1 =(const float*)d_in[5];
  const float* b1n=(const float*)d_in[6];
  const float* g2 =(const float*)d_in[7];
  const float* b2n=(const float*)d_in[8];
  const float* gg =(const float*)d_in[9];
  const float* gb =(const float*)d_in[10];
  const float* W1 =(const float*)d_in[11];
  const float* bb1=(const float*)d_in[12];
  const float* W2 =(const float*)d_in[13];
  const float* bb2=(const float*)d_in[14];
  float* out=(float*)d_out;

  char* ws=(char*)d_ws;
  size_t o=0;
  float*  x      =(float*) (ws+o); o+=(size_t)N*64*4;    // post-LN2 features
  float*  a1     =(float*) (ws+o); o+=(size_t)N*64*4;    // activated GCN1 output
  float*  xn     =(float*) (ws+o); o+=(size_t)N*4;       // row norms of x
  float*  ew     =(float*) (ws+o); o+=(size_t)N*3*4;     // knn edge weights
  float*  dis    =(float*) (ws+o); o+=(size_t)N*4;       // 1/sqrt(deg)
  int*    knn    =(int*)   (ws+o); o+=(size_t)N*3*4;     // neighbor indices
  float4* c4     =(float4*)(ws+o); o+=(size_t)N*16;      // (x,y,z,sq) original order
  float4* sc4    =(float4*)(ws+o); o+=(size_t)N*16;      // cell-sorted
  int*    sidx   =(int*)   (ws+o); o+=(size_t)N*4;       // sorted -> original
  int*    cellSt =(int*)   (ws+o); o+=(size_t)(NCELL+1)*4;
  (void)ws_size; (void)in_sizes; (void)n_in; (void)out_size;

  hipLaunchKernelGGL(prep_ln, dim3(NSCB+NLNB), dim3(256), 0, stream,
                     feat,g1,b1n,g2,b2n,coords,x,xn,c4,sc4,sidx,cellSt);
  hipLaunchKernelGGL(knn_ew,  dim3(2048),      dim3(256), 0, stream,
                     sc4,sidx,cellSt,c4,x,xn,knn,ew,dis);
  hipLaunchKernelGGL(agg1_w1, dim3(N/16),      dim3(256), 0, stream,
                     x,ew,dis,knn,W1,bb1,gg,gb,a1);
  hipLaunchKernelGGL(agg2_w2, dim3(N/16),      dim3(256), 0, stream,
                     a1,ew,dis,knn,W2,bb2,x,out);
}